// Round 3
// baseline (624.099 us; speedup 1.0000x reference)
//
#include <hip/hip_runtime.h>
#include <math.h>

// ---------------------------------------------------------------- types
typedef __bf16 bf16_t;
typedef bf16_t bf16x8 __attribute__((ext_vector_type(8)));
typedef float f32x4 __attribute__((ext_vector_type(4)));

#define S_LEN 2048
#define NHEAD 16
#define DHEAD 64
#define DMODEL 1024
#define BATCH 2

__device__ __forceinline__ float bf2f(unsigned short u) {
    unsigned int x = ((unsigned int)u) << 16;
    return __builtin_bit_cast(float, x);
}
__device__ __forceinline__ unsigned short f2bf(float f) {
    unsigned int x = __builtin_bit_cast(unsigned int, f);
    x += 0x7fffu + ((x >> 16) & 1u);          // RNE
    return (unsigned short)(x >> 16);
}

#define LDSTRIDE 56   // 32 payload + 24 pad shorts; 112B row -> 4-bank rotation

// ---------------------------------------------------------------- fused QKV GEMM
// x[M][K] fp32, W*[N][K] fp32. blockIdx.x in [0,24): which = x>>3 selects Q/K/V.
// Q,K: RoPE applied in epilogue, written [B,H,S,Dh] bf16.
// V  : written transposed [B,H,Dh,S] bf16 (packed 8B stores along s).
__global__ __launch_bounds__(256) void qkv_gemm_kernel(
    const float* __restrict__ x,
    const float* __restrict__ Wq, const float* __restrict__ bq,
    const float* __restrict__ Wk, const float* __restrict__ bk,
    const float* __restrict__ Wv, const float* __restrict__ bv,
    unsigned short* __restrict__ Qr, unsigned short* __restrict__ Kr,
    unsigned short* __restrict__ VT)
{
    __shared__ __align__(16) unsigned short As[128 * LDSTRIDE];
    __shared__ __align__(16) unsigned short Bs[128 * LDSTRIDE];

    const int which = blockIdx.x >> 3;            // 0=Q 1=K 2=V
    const int bnl   = (blockIdx.x & 7) * 128;     // col offset within this matrix
    const int bm    = blockIdx.y * 128;

    const float* W    = (which == 0) ? Wq : (which == 1) ? Wk : Wv;
    const float* bias = (which == 0) ? bq : (which == 1) ? bk : bv;

    const int tid  = threadIdx.x;
    const int lane = tid & 63;
    const int w    = tid >> 6;
    const int quad = lane >> 4;
    const int l16  = lane & 15;
    const int wm   = (w >> 1) * 64;
    const int wn   = (w & 1) * 64;

    f32x4 acc[4][4];
#pragma unroll
    for (int i = 0; i < 4; ++i)
#pragma unroll
        for (int j = 0; j < 4; ++j)
            acc[i][j] = f32x4{0.f, 0.f, 0.f, 0.f};

    const int r_st = tid >> 1;
    const int h_st = (tid & 1) * 16;

    for (int k0 = 0; k0 < DMODEL; k0 += 32) {
        __syncthreads();
#pragma unroll
        for (int j = 0; j < 4; ++j) {
            float4 v = *(const float4*)(x + (size_t)(bm + r_st) * DMODEL + k0 + h_st + j * 4);
            ushort4 o;
            o.x = f2bf(v.x); o.y = f2bf(v.y); o.z = f2bf(v.z); o.w = f2bf(v.w);
            *(ushort4*)(&As[r_st * LDSTRIDE + h_st + j * 4]) = o;
        }
#pragma unroll
        for (int j = 0; j < 4; ++j) {
            float4 v = *(const float4*)(W + (size_t)(bnl + r_st) * DMODEL + k0 + h_st + j * 4);
            ushort4 o;
            o.x = f2bf(v.x); o.y = f2bf(v.y); o.z = f2bf(v.z); o.w = f2bf(v.w);
            *(ushort4*)(&Bs[r_st * LDSTRIDE + h_st + j * 4]) = o;
        }
        __syncthreads();

        bf16x8 aF[4], bF[4];
#pragma unroll
        for (int t = 0; t < 4; ++t) {
            aF[t] = *(const bf16x8*)(&As[(wm + t * 16 + l16) * LDSTRIDE + quad * 8]);
            bF[t] = *(const bf16x8*)(&Bs[(wn + t * 16 + l16) * LDSTRIDE + quad * 8]);
        }
#pragma unroll
        for (int mt = 0; mt < 4; ++mt)
#pragma unroll
            for (int nt = 0; nt < 4; ++nt)
                acc[mt][nt] = __builtin_amdgcn_mfma_f32_16x16x32_bf16(
                    aF[mt], bF[nt], acc[mt][nt], 0, 0, 0);
    }

    // ---- epilogue
    const int h = (bnl + wn) >> 6;                // head index 0..15

    if (which < 2) {
        // RoPE: pair (d, d+32) = (nt, nt+2) same lane. d = nt*16+l16 for nt in {0,1}
        unsigned short* Dst = (which == 0) ? Qr : Kr;
        float freq[2];
#pragma unroll
        for (int nt = 0; nt < 2; ++nt) {
            const float d = (float)(nt * 16 + l16);
            freq[nt] = exp2f(-0.4152410119f * d);   // 10000^(-d/32)
        }
#pragma unroll
        for (int mt = 0; mt < 4; ++mt) {
            const int row0 = bm + wm + mt * 16 + quad * 4;
#pragma unroll
            for (int nt = 0; nt < 2; ++nt) {
                const int d   = nt * 16 + l16;
                const int cb  = bnl + wn + nt * 16 + l16;
                const float b1 = bias[cb];
                const float b2 = bias[cb + 32];
#pragma unroll
                for (int r = 0; r < 4; ++r) {
                    const int row = row0 + r;
                    const int bb = row >> 11, s = row & (S_LEN - 1);
                    const float ang = (float)s * freq[nt];
                    const float sn = sinf(ang);
                    const float cs = cosf(ang);
                    const float x1 = acc[mt][nt][r] + b1;
                    const float x2 = acc[mt][nt + 2][r] + b2;
                    const size_t base = ((size_t)(bb * NHEAD + h) * S_LEN + s) * DHEAD + d;
                    Dst[base]      = f2bf(x1 * cs - x2 * sn);
                    Dst[base + 32] = f2bf(x2 * cs + x1 * sn);
                }
            }
        }
    } else {
        // V transposed: VT[b][h][d][s], pack 4 consecutive s (r=0..3) into 8B
#pragma unroll
        for (int mt = 0; mt < 4; ++mt) {
            const int row0 = bm + wm + mt * 16 + quad * 4;
            const int bb = row0 >> 11, s0 = row0 & (S_LEN - 1);
#pragma unroll
            for (int nt = 0; nt < 4; ++nt) {
                const int d  = nt * 16 + l16;
                const float bv2 = bias[bnl + wn + nt * 16 + l16];
                unsigned short pk[4];
#pragma unroll
                for (int r = 0; r < 4; ++r)
                    pk[r] = f2bf(acc[mt][nt][r] + bv2);
                *(uint2*)(&VT[((size_t)(bb * NHEAD + h) * DHEAD + d) * S_LEN + s0]) =
                    *(const uint2*)pk;
            }
        }
    }
}

// ---------------------------------------------------------------- attention
// Q,K: [B,H,S,Dh] bf16 (RoPE'd).  VT: [B,H,Dh,S] bf16.  Out AO: [B,S,H*Dh] bf16.
// 4 waves, 64 Q-rows/block (16/wave), K-tile = 128, flash-style causal.
#define KSTR 72    // Ks row stride (shorts): 64+8
#define VSTR 136   // Vt/Pb row stride (shorts): 128+8
#define SCALE2 0.1803368801f   // 1/sqrt(64) * log2(e)

__global__ __launch_bounds__(256) void attn_kernel(
    const unsigned short* __restrict__ Q, const unsigned short* __restrict__ K,
    const unsigned short* __restrict__ VT, unsigned short* __restrict__ O)
{
    const int qt = blockIdx.x;
    const int h  = blockIdx.y;
    const int b  = blockIdx.z;
    const int tid  = threadIdx.x;
    const int w    = tid >> 6;
    const int lane = tid & 63;
    const int quad = lane >> 4;
    const int l16  = lane & 15;

    __shared__ __align__(16) unsigned short Ks[128 * KSTR];   // [kpos][dh]
    __shared__ __align__(16) unsigned short Vt[64 * VSTR];    // [dh][kpos]
    __shared__ __align__(16) unsigned short Pb[4 * 16 * VSTR];// per-wave P

    const int q0 = qt * 64;
    const size_t hb = (size_t)(b * NHEAD + h);
    const unsigned short* Qh = Q  + hb * S_LEN * DHEAD;
    const unsigned short* Kh = K  + hb * S_LEN * DHEAD;
    const unsigned short* Vh = VT + hb * DHEAD * S_LEN;

    const int qrow = q0 + w * 16 + l16;
    const bf16x8 qf0 = *(const bf16x8*)(Qh + (size_t)qrow * DHEAD + quad * 8);
    const bf16x8 qf1 = *(const bf16x8*)(Qh + (size_t)qrow * DHEAD + 32 + quad * 8);

    f32x4 o[4];
#pragma unroll
    for (int i = 0; i < 4; ++i) o[i] = f32x4{0.f, 0.f, 0.f, 0.f};
    float m_i[4], l_i[4];
#pragma unroll
    for (int r = 0; r < 4; ++r) { m_i[r] = -INFINITY; l_i[r] = 0.f; }

    const int nkt = (q0 + 64 + 127) >> 7;   // number of 128-wide k tiles

    // staging indices (4 x 16B chunks each for K and VT)
    uint4 kreg[4], vreg[4];
#pragma unroll
    for (int i = 0; i < 4; ++i) {
        const int idx = tid + i * 256;
        kreg[i] = *(const uint4*)(Kh + (size_t)(idx >> 3) * DHEAD + (idx & 7) * 8);
        vreg[i] = *(const uint4*)(Vh + (size_t)(idx >> 4) * S_LEN + (idx & 15) * 8);
    }

    for (int kt = 0; kt < nkt; ++kt) {
        __syncthreads();   // prev iter's readers done
#pragma unroll
        for (int i = 0; i < 4; ++i) {
            const int idx = tid + i * 256;
            *(uint4*)(&Ks[(idx >> 3) * KSTR + (idx & 7) * 8]) = kreg[i];
            *(uint4*)(&Vt[(idx >> 4) * VSTR + (idx & 15) * 8]) = vreg[i];
        }
        __syncthreads();   // tile staged
        if (kt + 1 < nkt) {
            const int base = (kt + 1) * 128;
#pragma unroll
            for (int i = 0; i < 4; ++i) {
                const int idx = tid + i * 256;
                kreg[i] = *(const uint4*)(Kh + (size_t)(base + (idx >> 3)) * DHEAD + (idx & 7) * 8);
                vreg[i] = *(const uint4*)(Vh + (size_t)(idx >> 4) * S_LEN + base + (idx & 15) * 8);
            }
        }

        // ---- scores: 16 q-rows x 128 k per wave
        f32x4 sc[8];
#pragma unroll
        for (int nt = 0; nt < 8; ++nt) {
            const bf16x8 kf0 = *(const bf16x8*)(&Ks[(nt * 16 + l16) * KSTR + quad * 8]);
            const bf16x8 kf1 = *(const bf16x8*)(&Ks[(nt * 16 + l16) * KSTR + 32 + quad * 8]);
            f32x4 a = f32x4{0.f, 0.f, 0.f, 0.f};
            a = __builtin_amdgcn_mfma_f32_16x16x32_bf16(qf0, kf0, a, 0, 0, 0);
            a = __builtin_amdgcn_mfma_f32_16x16x32_bf16(qf1, kf1, a, 0, 0, 0);
            sc[nt] = a;
        }
#pragma unroll
        for (int nt = 0; nt < 8; ++nt)
#pragma unroll
            for (int r = 0; r < 4; ++r)
                sc[nt][r] *= SCALE2;                       // base-2 domain

        const int qpos0 = q0 + w * 16 + quad * 4;
        if (kt == nkt - 1) {                               // ragged causal edge
#pragma unroll
            for (int nt = 0; nt < 8; ++nt) {
                const int kpos = kt * 128 + nt * 16 + l16;
#pragma unroll
                for (int r = 0; r < 4; ++r)
                    if (kpos > qpos0 + r) sc[nt][r] = -INFINITY;
            }
        }

        // ---- online softmax (base-2); rows live in 16-lane groups
        float mnew[4], alpha[4];
#pragma unroll
        for (int r = 0; r < 4; ++r) {
            float mx = sc[0][r];
#pragma unroll
            for (int nt = 1; nt < 8; ++nt) mx = fmaxf(mx, sc[nt][r]);
#pragma unroll
            for (int msk = 1; msk < 16; msk <<= 1)
                mx = fmaxf(mx, __shfl_xor(mx, msk));
            mnew[r]  = fmaxf(m_i[r], mx);
            alpha[r] = exp2f(m_i[r] - mnew[r]);
            m_i[r]   = mnew[r];
        }
#pragma unroll
        for (int nt = 0; nt < 8; ++nt)
#pragma unroll
            for (int r = 0; r < 4; ++r)
                sc[nt][r] = exp2f(sc[nt][r] - mnew[r]);
#pragma unroll
        for (int r = 0; r < 4; ++r) {
            float rs = 0.f;
#pragma unroll
            for (int nt = 0; nt < 8; ++nt) rs += sc[nt][r];
#pragma unroll
            for (int msk = 1; msk < 16; msk <<= 1)
                rs += __shfl_xor(rs, msk);
            l_i[r] = l_i[r] * alpha[r] + rs;
        }
#pragma unroll
        for (int nt = 0; nt < 4; ++nt)
#pragma unroll
            for (int r = 0; r < 4; ++r)
                o[nt][r] *= alpha[r];

        // ---- P: C-layout -> per-wave LDS -> A-layout (no barrier: Pb[w] is wave-private)
        unsigned short* Pw = &Pb[w * 16 * VSTR];
#pragma unroll
        for (int nt = 0; nt < 8; ++nt)
#pragma unroll
            for (int r = 0; r < 4; ++r)
                Pw[(quad * 4 + r) * VSTR + nt * 16 + l16] = f2bf(sc[nt][r]);

        bf16x8 pA[4];
#pragma unroll
        for (int c = 0; c < 4; ++c)
            pA[c] = *(const bf16x8*)(&Pw[l16 * VSTR + c * 32 + quad * 8]);
#pragma unroll
        for (int nt = 0; nt < 4; ++nt) {
#pragma unroll
            for (int c = 0; c < 4; ++c) {
                const bf16x8 vF = *(const bf16x8*)(&Vt[(nt * 16 + l16) * VSTR + c * 32 + quad * 8]);
                o[nt] = __builtin_amdgcn_mfma_f32_16x16x32_bf16(pA[c], vF, o[nt], 0, 0, 0);
            }
        }
    }

    // ---- epilogue
    float linv[4];
#pragma unroll
    for (int r = 0; r < 4; ++r) linv[r] = 1.0f / l_i[r];
    const int spos0 = q0 + w * 16 + quad * 4;
#pragma unroll
    for (int nt = 0; nt < 4; ++nt)
#pragma unroll
        for (int r = 0; r < 4; ++r) {
            const float val = o[nt][r] * linv[r];
            O[((size_t)b * S_LEN + spos0 + r) * DMODEL + h * DHEAD + nt * 16 + l16] = f2bf(val);
        }
}

// ---------------------------------------------------------------- out-proj GEMM
// C[M][N] fp32 = A[M][K](bf16) * B[N][K](fp32)^T + bias.  Tile 64x128, grid (8,64).
__global__ __launch_bounds__(256) void outproj_kernel(
    const unsigned short* __restrict__ A, const float* __restrict__ Bw,
    const float* __restrict__ bias, float* __restrict__ C,
    int M, int N, int K)
{
    __shared__ __align__(16) unsigned short As[64 * LDSTRIDE];
    __shared__ __align__(16) unsigned short Bs[128 * LDSTRIDE];

    const int tid  = threadIdx.x;
    const int lane = tid & 63;
    const int w    = tid >> 6;
    const int quad = lane >> 4;
    const int l16  = lane & 15;
    const int wm   = (w >> 1) * 32;   // 2x2 waves, each 32x64
    const int wn   = (w & 1) * 64;
    const int bm   = blockIdx.y * 64;
    const int bn   = blockIdx.x * 128;

    f32x4 acc[2][4];
#pragma unroll
    for (int i = 0; i < 2; ++i)
#pragma unroll
        for (int j = 0; j < 4; ++j)
            acc[i][j] = f32x4{0.f, 0.f, 0.f, 0.f};

    for (int k0 = 0; k0 < K; k0 += 32) {
        __syncthreads();
        {   // A: 64 rows x 32 cols bf16 -> 256 chunks of 16B, 1/thread
            const int r = tid >> 2, c = (tid & 3) * 8;
            *(uint4*)(&As[r * LDSTRIDE + c]) =
                *(const uint4*)(A + (size_t)(bm + r) * K + k0 + c);
        }
#pragma unroll
        for (int i = 0; i < 4; ++i) {   // B: 128 rows x 32 cols fp32
            const int idx = tid + i * 256;
            const int r = idx >> 3, c = (idx & 7) * 4;
            float4 v = *(const float4*)(Bw + (size_t)(bn + r) * K + k0 + c);
            ushort4 o;
            o.x = f2bf(v.x); o.y = f2bf(v.y); o.z = f2bf(v.z); o.w = f2bf(v.w);
            *(ushort4*)(&Bs[r * LDSTRIDE + c]) = o;
        }
        __syncthreads();

        bf16x8 aF[2], bF[4];
#pragma unroll
        for (int t = 0; t < 2; ++t)
            aF[t] = *(const bf16x8*)(&As[(wm + t * 16 + l16) * LDSTRIDE + quad * 8]);
#pragma unroll
        for (int t = 0; t < 4; ++t)
            bF[t] = *(const bf16x8*)(&Bs[(wn + t * 16 + l16) * LDSTRIDE + quad * 8]);
#pragma unroll
        for (int mt = 0; mt < 2; ++mt)
#pragma unroll
            for (int nt = 0; nt < 4; ++nt)
                acc[mt][nt] = __builtin_amdgcn_mfma_f32_16x16x32_bf16(
                    aF[mt], bF[nt], acc[mt][nt], 0, 0, 0);
    }

#pragma unroll
    for (int mt = 0; mt < 2; ++mt) {
        const int row0 = bm + wm + mt * 16 + quad * 4;
#pragma unroll
        for (int nt = 0; nt < 4; ++nt) {
            const int col = bn + wn + nt * 16 + l16;
            const float bv = bias[col];
#pragma unroll
            for (int r = 0; r < 4; ++r)
                C[(size_t)(row0 + r) * N + col] = acc[mt][nt][r] + bv;
        }
    }
}

// ---------------------------------------------------------------- launch
extern "C" void kernel_launch(void* const* d_in, const int* in_sizes, int n_in,
                              void* d_out, int out_size, void* d_ws, size_t ws_size,
                              hipStream_t stream) {
    const float* x  = (const float*)d_in[0];
    const float* Wq = (const float*)d_in[1];
    const float* bq = (const float*)d_in[2];
    const float* Wk = (const float*)d_in[3];
    const float* bk = (const float*)d_in[4];
    const float* Wv = (const float*)d_in[5];
    const float* bv = (const float*)d_in[6];
    const float* Wo = (const float*)d_in[7];
    const float* bo = (const float*)d_in[8];
    float* out = (float*)d_out;

    char* ws = (char*)d_ws;
    const size_t SZ = (size_t)BATCH * S_LEN * DMODEL * sizeof(unsigned short); // 8 MB
    unsigned short* Qr = (unsigned short*)(ws);
    unsigned short* Kr = (unsigned short*)(ws + SZ);
    unsigned short* VT = (unsigned short*)(ws + 2 * SZ);
    unsigned short* AO = (unsigned short*)(ws + 3 * SZ);

    const int M = BATCH * S_LEN;   // 4096

    qkv_gemm_kernel<<<dim3(24, M / 128), 256, 0, stream>>>(
        x, Wq, bq, Wk, bk, Wv, bv, Qr, Kr, VT);

    attn_kernel<<<dim3(S_LEN / 64, NHEAD, BATCH), 256, 0, stream>>>(Qr, Kr, VT, AO);

    outproj_kernel<<<dim3(DMODEL / 128, M / 64), 256, 0, stream>>>(
        AO, Wo, bo, out, M, DMODEL, DMODEL);
}

// Round 4
// 331.494 us; speedup vs baseline: 1.8827x; 1.8827x over previous
//
#include <hip/hip_runtime.h>
#include <math.h>

// ---------------------------------------------------------------- types
typedef __bf16 bf16_t;
typedef bf16_t bf16x8 __attribute__((ext_vector_type(8)));
typedef float f32x4 __attribute__((ext_vector_type(4)));

#define S_LEN 2048
#define NHEAD 16
#define DHEAD 64
#define DMODEL 1024
#define BATCH 2

__device__ __forceinline__ float bf2f(unsigned short u) {
    unsigned int x = ((unsigned int)u) << 16;
    return __builtin_bit_cast(float, x);
}
__device__ __forceinline__ unsigned short f2bf(float f) {
    unsigned int x = __builtin_bit_cast(unsigned int, f);
    x += 0x7fffu + ((x >> 16) & 1u);          // RNE
    return (unsigned short)(x >> 16);
}

// async global->LDS, 16B per lane. LDS dest must be wave-uniform base + lane*16.
__device__ __forceinline__ void glds16(const void* g, void* l) {
    __builtin_amdgcn_global_load_lds(
        (__attribute__((address_space(1))) void*)g,
        (__attribute__((address_space(3))) void*)l,
        16, 0, 0);
}

// ---------------------------------------------------------------- fp32 -> bf16 convert
// y=0: x (4M el), y=1..4: Wq,Wk,Wv,Wo (1M el each)
__global__ __launch_bounds__(256) void cvt_kernel(
    const float* __restrict__ x,  const float* __restrict__ wq,
    const float* __restrict__ wk, const float* __restrict__ wv,
    const float* __restrict__ wo,
    unsigned short* __restrict__ xb,  unsigned short* __restrict__ wqb,
    unsigned short* __restrict__ wkb, unsigned short* __restrict__ wvb,
    unsigned short* __restrict__ wob)
{
    const int y = blockIdx.y;
    const float* s = (y == 0) ? x : (y == 1) ? wq : (y == 2) ? wk : (y == 3) ? wv : wo;
    unsigned short* d = (y == 0) ? xb : (y == 1) ? wqb : (y == 2) ? wkb : (y == 3) ? wvb : wob;
    const int n4 = (y == 0) ? (1 << 20) : (1 << 18);
    const int i = blockIdx.x * 256 + threadIdx.x;
    if (i < n4) {
        float4 v = ((const float4*)s)[i];
        ushort4 o;
        o.x = f2bf(v.x); o.y = f2bf(v.y); o.z = f2bf(v.z); o.w = f2bf(v.w);
        ((ushort4*)d)[i] = o;
    }
}

// ---------------------------------------------------------------- RoPE cos/sin table
// tab[s*32+d] = {cos(s*freq_d), sin(s*freq_d)}, freq_d = 10000^(-d/32)
__global__ __launch_bounds__(256) void rope_table_kernel(float2* __restrict__ tab)
{
    const int gid = blockIdx.x * 256 + threadIdx.x;   // 65536
    const int s = gid >> 5, d = gid & 31;
    const float freq = exp2f(-0.4152410119f * (float)d);
    const float ang = (float)s * freq;
    tab[gid] = make_float2(cosf(ang), sinf(ang));
}

// ---------------------------------------------------------------- fused QKV GEMM (bf16 in, glds staging)
// xb[M][1024] bf16, W*b[1024][1024] bf16. which=blockIdx.x>>3 selects Q/K/V.
// Output: Y* [B,S,1024] bf16 row-major (bias added). 128x128 tile, BK=32.
__global__ __launch_bounds__(256) void qkv_gemm_kernel(
    const unsigned short* __restrict__ xb,
    const unsigned short* __restrict__ wqb, const unsigned short* __restrict__ wkb,
    const unsigned short* __restrict__ wvb,
    const float* __restrict__ bq, const float* __restrict__ bk, const float* __restrict__ bv,
    unsigned short* __restrict__ Yq, unsigned short* __restrict__ Yk,
    unsigned short* __restrict__ Yv)
{
    __shared__ __align__(16) unsigned short As[128 * 32];   // unpadded (glds constraint)
    __shared__ __align__(16) unsigned short Bs[128 * 32];

    const int which = blockIdx.x >> 3;
    const int bn = (blockIdx.x & 7) * 128;
    const int bm = blockIdx.y * 128;
    const unsigned short* W = (which == 0) ? wqb : (which == 1) ? wkb : wvb;
    const float* bias       = (which == 0) ? bq  : (which == 1) ? bk  : bv;
    unsigned short* Y       = (which == 0) ? Yq  : (which == 1) ? Yk  : Yv;

    const int tid  = threadIdx.x;
    const int lane = tid & 63;
    const int w    = tid >> 6;
    const int quad = lane >> 4;
    const int l16  = lane & 15;
    const int wm   = (w >> 1) * 64;
    const int wn   = (w & 1) * 64;

    f32x4 acc[4][4];
#pragma unroll
    for (int i = 0; i < 4; ++i)
#pragma unroll
        for (int j = 0; j < 4; ++j)
            acc[i][j] = f32x4{0.f, 0.f, 0.f, 0.f};

    // chunk tid covers (row=tid>>2, col16=tid&3); chunk tid+256 -> row+64
    const int r0 = tid >> 2, c0 = (tid & 3) * 8;
    const unsigned short* ga0 = xb + (size_t)(bm + r0) * DMODEL + c0;
    const unsigned short* ga1 = ga0 + (size_t)64 * DMODEL;
    const unsigned short* gb0 = W  + (size_t)(bn + r0) * DMODEL + c0;
    const unsigned short* gb1 = gb0 + (size_t)64 * DMODEL;
    unsigned short* la0 = As + tid * 8;
    unsigned short* la1 = As + (tid + 256) * 8;
    unsigned short* lb0 = Bs + tid * 8;
    unsigned short* lb1 = Bs + (tid + 256) * 8;

    for (int k0 = 0; k0 < DMODEL; k0 += 32) {
        glds16(ga0 + k0, la0);
        glds16(ga1 + k0, la1);
        glds16(gb0 + k0, lb0);
        glds16(gb1 + k0, lb1);
        __syncthreads();

        bf16x8 aF[4], bF[4];
#pragma unroll
        for (int t = 0; t < 4; ++t) {
            aF[t] = *(const bf16x8*)(&As[(wm + t * 16 + l16) * 32 + quad * 8]);
            bF[t] = *(const bf16x8*)(&Bs[(wn + t * 16 + l16) * 32 + quad * 8]);
        }
#pragma unroll
        for (int mt = 0; mt < 4; ++mt)
#pragma unroll
            for (int nt = 0; nt < 4; ++nt)
                acc[mt][nt] = __builtin_amdgcn_mfma_f32_16x16x32_bf16(
                    aF[mt], bF[nt], acc[mt][nt], 0, 0, 0);
        __syncthreads();
    }

#pragma unroll
    for (int mt = 0; mt < 4; ++mt) {
        const int row0 = bm + wm + mt * 16 + quad * 4;
#pragma unroll
        for (int nt = 0; nt < 4; ++nt) {
            const int col = bn + wn + nt * 16 + l16;
            const float bv = bias[col];
#pragma unroll
            for (int r = 0; r < 4; ++r)
                Y[(size_t)(row0 + r) * DMODEL + col] = f2bf(acc[mt][nt][r] + bv);
        }
    }
}

// ---------------------------------------------------------------- RoPE (table-driven)
// Y [B,S,1024] bf16 -> O [B,H,S,Dh] bf16. thread: (b,s,h,c), c in [0,8): d=c*4..c*4+3
__global__ __launch_bounds__(256) void rope_kernel(
    const unsigned short* __restrict__ Yq, const unsigned short* __restrict__ Yk,
    const float2* __restrict__ tab,
    unsigned short* __restrict__ Qr, unsigned short* __restrict__ Kr)
{
    const unsigned short* Y = blockIdx.y ? Yk : Yq;
    unsigned short* O = blockIdx.y ? Kr : Qr;
    const int gid = blockIdx.x * 256 + threadIdx.x;   // B*S*128 = 524288
    const int c = gid & 7;
    const int h = (gid >> 3) & 15;
    const int s = (gid >> 7) & (S_LEN - 1);
    const int b = gid >> 18;

    const size_t ib = ((size_t)(b * S_LEN + s)) * DMODEL + h * DHEAD + c * 4;
    union { uint2 u; unsigned short e[4]; } u1, u2, o1, o2;
    u1.u = *(const uint2*)(Y + ib);
    u2.u = *(const uint2*)(Y + ib + 32);
#pragma unroll
    for (int j = 0; j < 4; ++j) {
        const float2 cs = tab[s * 32 + c * 4 + j];
        const float x1 = bf2f(u1.e[j]);
        const float x2 = bf2f(u2.e[j]);
        o1.e[j] = f2bf(x1 * cs.x - x2 * cs.y);
        o2.e[j] = f2bf(x2 * cs.x + x1 * cs.y);
    }
    const size_t ob = (((size_t)(b * NHEAD + h)) * S_LEN + s) * DHEAD + c * 4;
    *(uint2*)(O + ob)      = o1.u;
    *(uint2*)(O + ob + 32) = o2.u;
}

// ---------------------------------------------------------------- V transpose
// Yv [B,S,1024] -> VT [B,H,Dh,S]. 64x64 tiles via LDS.
__global__ __launch_bounds__(256) void vtrans_kernel(
    const unsigned short* __restrict__ Yv, unsigned short* __restrict__ VT)
{
    __shared__ unsigned short T[64 * 88];   // [d][s'], stride 88 (176B, 16B-aligned)
    const int s0 = blockIdx.x * 64, h = blockIdx.y, b = blockIdx.z;
    const int tid = threadIdx.x;
#pragma unroll
    for (int k = 0; k < 2; ++k) {
        const int i = tid + k * 256;
        const int sr = i >> 3, c = i & 7;
        union { uint4 u; unsigned short e[8]; } v;
        v.u = *(const uint4*)(Yv + ((size_t)(b * S_LEN + s0 + sr)) * DMODEL + h * DHEAD + c * 8);
#pragma unroll
        for (int j = 0; j < 8; ++j)
            T[(c * 8 + j) * 88 + sr] = v.e[j];
    }
    __syncthreads();
#pragma unroll
    for (int k = 0; k < 2; ++k) {
        const int i = tid + k * 256;
        const int d = i >> 3, cs = i & 7;
        uint4 u = *(const uint4*)(&T[d * 88 + cs * 8]);
        *(uint4*)(VT + (((size_t)(b * NHEAD + h)) * DHEAD + d) * S_LEN + s0 + cs * 8) = u;
    }
}

// ---------------------------------------------------------------- attention (round-3, verified)
#define KSTR 72    // Ks row stride (shorts): 64+8
#define VSTR 136   // Vt/Pb row stride (shorts): 128+8
#define SCALE2 0.1803368801f   // 1/sqrt(64) * log2(e)

__global__ __launch_bounds__(256) void attn_kernel(
    const unsigned short* __restrict__ Q, const unsigned short* __restrict__ K,
    const unsigned short* __restrict__ VT, unsigned short* __restrict__ O)
{
    const int qt = blockIdx.x;
    const int h  = blockIdx.y;
    const int b  = blockIdx.z;
    const int tid  = threadIdx.x;
    const int w    = tid >> 6;
    const int lane = tid & 63;
    const int quad = lane >> 4;
    const int l16  = lane & 15;

    __shared__ __align__(16) unsigned short Ks[128 * KSTR];
    __shared__ __align__(16) unsigned short Vt[64 * VSTR];
    __shared__ __align__(16) unsigned short Pb[4 * 16 * VSTR];

    const int q0 = qt * 64;
    const size_t hb = (size_t)(b * NHEAD + h);
    const unsigned short* Qh = Q  + hb * S_LEN * DHEAD;
    const unsigned short* Kh = K  + hb * S_LEN * DHEAD;
    const unsigned short* Vh = VT + hb * DHEAD * S_LEN;

    const int qrow = q0 + w * 16 + l16;
    const bf16x8 qf0 = *(const bf16x8*)(Qh + (size_t)qrow * DHEAD + quad * 8);
    const bf16x8 qf1 = *(const bf16x8*)(Qh + (size_t)qrow * DHEAD + 32 + quad * 8);

    f32x4 o[4];
#pragma unroll
    for (int i = 0; i < 4; ++i) o[i] = f32x4{0.f, 0.f, 0.f, 0.f};
    float m_i[4], l_i[4];
#pragma unroll
    for (int r = 0; r < 4; ++r) { m_i[r] = -INFINITY; l_i[r] = 0.f; }

    const int nkt = (q0 + 64 + 127) >> 7;

    uint4 kreg[4], vreg[4];
#pragma unroll
    for (int i = 0; i < 4; ++i) {
        const int idx = tid + i * 256;
        kreg[i] = *(const uint4*)(Kh + (size_t)(idx >> 3) * DHEAD + (idx & 7) * 8);
        vreg[i] = *(const uint4*)(Vh + (size_t)(idx >> 4) * S_LEN + (idx & 15) * 8);
    }

    for (int kt = 0; kt < nkt; ++kt) {
        __syncthreads();
#pragma unroll
        for (int i = 0; i < 4; ++i) {
            const int idx = tid + i * 256;
            *(uint4*)(&Ks[(idx >> 3) * KSTR + (idx & 7) * 8]) = kreg[i];
            *(uint4*)(&Vt[(idx >> 4) * VSTR + (idx & 15) * 8]) = vreg[i];
        }
        __syncthreads();
        if (kt + 1 < nkt) {
            const int base = (kt + 1) * 128;
#pragma unroll
            for (int i = 0; i < 4; ++i) {
                const int idx = tid + i * 256;
                kreg[i] = *(const uint4*)(Kh + (size_t)(base + (idx >> 3)) * DHEAD + (idx & 7) * 8);
                vreg[i] = *(const uint4*)(Vh + (size_t)(idx >> 4) * S_LEN + base + (idx & 15) * 8);
            }
        }

        f32x4 sc[8];
#pragma unroll
        for (int nt = 0; nt < 8; ++nt) {
            const bf16x8 kf0 = *(const bf16x8*)(&Ks[(nt * 16 + l16) * KSTR + quad * 8]);
            const bf16x8 kf1 = *(const bf16x8*)(&Ks[(nt * 16 + l16) * KSTR + 32 + quad * 8]);
            f32x4 a = f32x4{0.f, 0.f, 0.f, 0.f};
            a = __builtin_amdgcn_mfma_f32_16x16x32_bf16(qf0, kf0, a, 0, 0, 0);
            a = __builtin_amdgcn_mfma_f32_16x16x32_bf16(qf1, kf1, a, 0, 0, 0);
            sc[nt] = a;
        }
#pragma unroll
        for (int nt = 0; nt < 8; ++nt)
#pragma unroll
            for (int r = 0; r < 4; ++r)
                sc[nt][r] *= SCALE2;

        const int qpos0 = q0 + w * 16 + quad * 4;
        if (kt == nkt - 1) {
#pragma unroll
            for (int nt = 0; nt < 8; ++nt) {
                const int kpos = kt * 128 + nt * 16 + l16;
#pragma unroll
                for (int r = 0; r < 4; ++r)
                    if (kpos > qpos0 + r) sc[nt][r] = -INFINITY;
            }
        }

        float mnew[4], alpha[4];
#pragma unroll
        for (int r = 0; r < 4; ++r) {
            float mx = sc[0][r];
#pragma unroll
            for (int nt = 1; nt < 8; ++nt) mx = fmaxf(mx, sc[nt][r]);
#pragma unroll
            for (int msk = 1; msk < 16; msk <<= 1)
                mx = fmaxf(mx, __shfl_xor(mx, msk));
            mnew[r]  = fmaxf(m_i[r], mx);
            alpha[r] = exp2f(m_i[r] - mnew[r]);
            m_i[r]   = mnew[r];
        }
#pragma unroll
        for (int nt = 0; nt < 8; ++nt)
#pragma unroll
            for (int r = 0; r < 4; ++r)
                sc[nt][r] = exp2f(sc[nt][r] - mnew[r]);
#pragma unroll
        for (int r = 0; r < 4; ++r) {
            float rs = 0.f;
#pragma unroll
            for (int nt = 0; nt < 8; ++nt) rs += sc[nt][r];
#pragma unroll
            for (int msk = 1; msk < 16; msk <<= 1)
                rs += __shfl_xor(rs, msk);
            l_i[r] = l_i[r] * alpha[r] + rs;
        }
#pragma unroll
        for (int nt = 0; nt < 4; ++nt)
#pragma unroll
            for (int r = 0; r < 4; ++r)
                o[nt][r] *= alpha[r];

        unsigned short* Pw = &Pb[w * 16 * VSTR];
#pragma unroll
        for (int nt = 0; nt < 8; ++nt)
#pragma unroll
            for (int r = 0; r < 4; ++r)
                Pw[(quad * 4 + r) * VSTR + nt * 16 + l16] = f2bf(sc[nt][r]);

        bf16x8 pA[4];
#pragma unroll
        for (int c = 0; c < 4; ++c)
            pA[c] = *(const bf16x8*)(&Pw[l16 * VSTR + c * 32 + quad * 8]);
#pragma unroll
        for (int nt = 0; nt < 4; ++nt) {
#pragma unroll
            for (int c = 0; c < 4; ++c) {
                const bf16x8 vF = *(const bf16x8*)(&Vt[(nt * 16 + l16) * VSTR + c * 32 + quad * 8]);
                o[nt] = __builtin_amdgcn_mfma_f32_16x16x32_bf16(pA[c], vF, o[nt], 0, 0, 0);
            }
        }
    }

    float linv[4];
#pragma unroll
    for (int r = 0; r < 4; ++r) linv[r] = 1.0f / l_i[r];
    const int spos0 = q0 + w * 16 + quad * 4;
#pragma unroll
    for (int nt = 0; nt < 4; ++nt)
#pragma unroll
        for (int r = 0; r < 4; ++r) {
            const float val = o[nt][r] * linv[r];
            O[((size_t)b * S_LEN + spos0 + r) * DMODEL + h * DHEAD + nt * 16 + l16] = f2bf(val);
        }
}

// ---------------------------------------------------------------- out-proj GEMM (bf16 x bf16 -> fp32)
// C[M][N] = AO[M][K] * Wo[N][K]^T + bo. 64x128 tile, glds staging.
__global__ __launch_bounds__(256) void outproj_kernel(
    const unsigned short* __restrict__ A, const unsigned short* __restrict__ W,
    const float* __restrict__ bias, float* __restrict__ C)
{
    __shared__ __align__(16) unsigned short As[64 * 32];
    __shared__ __align__(16) unsigned short Bs[128 * 32];

    const int tid  = threadIdx.x;
    const int lane = tid & 63;
    const int w    = tid >> 6;
    const int quad = lane >> 4;
    const int l16  = lane & 15;
    const int wm   = (w >> 1) * 32;
    const int wn   = (w & 1) * 64;
    const int bm   = blockIdx.y * 64;
    const int bn   = blockIdx.x * 128;

    f32x4 acc[2][4];
#pragma unroll
    for (int i = 0; i < 2; ++i)
#pragma unroll
        for (int j = 0; j < 4; ++j)
            acc[i][j] = f32x4{0.f, 0.f, 0.f, 0.f};

    const int r0 = tid >> 2, c0 = (tid & 3) * 8;
    const unsigned short* ga  = A + (size_t)(bm + r0) * DMODEL + c0;
    const unsigned short* gb0 = W + (size_t)(bn + r0) * DMODEL + c0;
    const unsigned short* gb1 = gb0 + (size_t)64 * DMODEL;
    unsigned short* la  = As + tid * 8;
    unsigned short* lb0 = Bs + tid * 8;
    unsigned short* lb1 = Bs + (tid + 256) * 8;

    for (int k0 = 0; k0 < DMODEL; k0 += 32) {
        glds16(ga + k0, la);
        glds16(gb0 + k0, lb0);
        glds16(gb1 + k0, lb1);
        __syncthreads();

        bf16x8 aF[2], bF[4];
#pragma unroll
        for (int t = 0; t < 2; ++t)
            aF[t] = *(const bf16x8*)(&As[(wm + t * 16 + l16) * 32 + quad * 8]);
#pragma unroll
        for (int t = 0; t < 4; ++t)
            bF[t] = *(const bf16x8*)(&Bs[(wn + t * 16 + l16) * 32 + quad * 8]);
#pragma unroll
        for (int mt = 0; mt < 2; ++mt)
#pragma unroll
            for (int nt = 0; nt < 4; ++nt)
                acc[mt][nt] = __builtin_amdgcn_mfma_f32_16x16x32_bf16(
                    aF[mt], bF[nt], acc[mt][nt], 0, 0, 0);
        __syncthreads();
    }

#pragma unroll
    for (int mt = 0; mt < 2; ++mt) {
        const int row0 = bm + wm + mt * 16 + quad * 4;
#pragma unroll
        for (int nt = 0; nt < 4; ++nt) {
            const int col = bn + wn + nt * 16 + l16;
            const float bv = bias[col];
#pragma unroll
            for (int r = 0; r < 4; ++r)
                C[(size_t)(row0 + r) * DMODEL + col] = acc[mt][nt][r] + bv;
        }
    }
}

// ---------------------------------------------------------------- launch
extern "C" void kernel_launch(void* const* d_in, const int* in_sizes, int n_in,
                              void* d_out, int out_size, void* d_ws, size_t ws_size,
                              hipStream_t stream) {
    const float* x  = (const float*)d_in[0];
    const float* Wq = (const float*)d_in[1];
    const float* bq = (const float*)d_in[2];
    const float* Wk = (const float*)d_in[3];
    const float* bk = (const float*)d_in[4];
    const float* Wv = (const float*)d_in[5];
    const float* bv = (const float*)d_in[6];
    const float* Wo = (const float*)d_in[7];
    const float* bo = (const float*)d_in[8];
    float* out = (float*)d_out;

    char* ws = (char*)d_ws;
    const size_t MB = 1 << 20;
    unsigned short* xb  = (unsigned short*)(ws);            //  8 MB
    unsigned short* wqb = (unsigned short*)(ws + 8  * MB);  //  2 MB
    unsigned short* wkb = (unsigned short*)(ws + 10 * MB);
    unsigned short* wvb = (unsigned short*)(ws + 12 * MB);
    unsigned short* wob = (unsigned short*)(ws + 14 * MB);
    float2*         tab = (float2*)       (ws + 16 * MB);   // 512 KB
    unsigned short* Yq  = (unsigned short*)(ws + 17 * MB);  //  8 MB
    unsigned short* Yk  = (unsigned short*)(ws + 25 * MB);
    unsigned short* Yv  = (unsigned short*)(ws + 33 * MB);
    unsigned short* Qr  = (unsigned short*)(ws + 41 * MB);
    unsigned short* Kr  = (unsigned short*)(ws + 49 * MB);
    unsigned short* VT  = (unsigned short*)(ws + 57 * MB);
    unsigned short* AO  = (unsigned short*)(ws + 33 * MB);  // alias Yv (consumed by vtrans first)

    const int M = BATCH * S_LEN;   // 4096

    cvt_kernel<<<dim3(4096, 5), 256, 0, stream>>>(
        x, Wq, Wk, Wv, Wo, xb, wqb, wkb, wvb, wob);

    rope_table_kernel<<<256, 256, 0, stream>>>(tab);

    qkv_gemm_kernel<<<dim3(24, M / 128), 256, 0, stream>>>(
        xb, wqb, wkb, wvb, bq, bk, bv, Yq, Yk, Yv);

    rope_kernel<<<dim3(2048, 2), 256, 0, stream>>>(Yq, Yk, tab, Qr, Kr);

    vtrans_kernel<<<dim3(S_LEN / 64, NHEAD, BATCH), 256, 0, stream>>>(Yv, VT);

    attn_kernel<<<dim3(S_LEN / 64, NHEAD, BATCH), 256, 0, stream>>>(Qr, Kr, VT, AO);

    outproj_kernel<<<dim3(DMODEL / 128, M / 64), 256, 0, stream>>>(AO, wob, bo, out);
}